// Round 7
// baseline (7866.196 us; speedup 1.0000x reference)
//
#include <hip/hip_runtime.h>

#define NWG     256
#define TPB     256
#define NL0     128          // WGs [0,128) = layer0, [128,256) = layer1
#define T_STEPS 1024
#define HD      1024
#define DIN     256
#define K0      1280         // DIN + HD   (40 kb-slices of 32)
#define K1      2048         // HD + HD    (64 kb-slices of 32)
#define K0P     1288         // padded LDS row stride (shorts)
#define K1P     2056
#define SCR_OFF (32*K1P*2)               // 131,584
#define SMEM_BYTES (SCR_OFF + 8192)      // + [4][64][2] f32x4 exchange scratch

#define HSLAB_BYTES 131072ull            // one h snapshot: 128 planes x 64 batch x 8 bf16
#define HSLAB_U64   16384
#define HIST_DEPTH  1025                 // slot(t)=(t+1)%1025 never wraps in 1024 steps
#define HIST_BYTES  (HIST_DEPTH*HSLAB_BYTES)   // 134,348,800
#define X8_BYTES    33554432ull
#define FLAGS_BYTES 32768ull

typedef float  f32x4  __attribute__((ext_vector_type(4)));
typedef __bf16 bf16x8 __attribute__((ext_vector_type(8)));
typedef int    i32x4  __attribute__((ext_vector_type(4)));
typedef unsigned long long u64;

__device__ __forceinline__ unsigned short f2bf(float f){
  union { float f; unsigned u; } a; a.f = f;
  unsigned u = a.u;
  u += 0x7fffu + ((u >> 16) & 1u);   // RNE
  return (unsigned short)(u >> 16);
}
__device__ __forceinline__ float sigmf(float x){ return 1.0f/(1.0f + __expf(-x)); }
__device__ __forceinline__ float tanhf_fast(float x){ return 2.0f*sigmf(2.0f*x) - 1.0f; }

// coherent (MALL-level, cross-XCD) accessors — per-access, no L2 invalidation
__device__ __forceinline__ u64 ld64c(const u64* p){
  return __hip_atomic_load(p, __ATOMIC_RELAXED, __HIP_MEMORY_SCOPE_AGENT);
}
__device__ __forceinline__ unsigned ldflag(const unsigned* p){
  return __hip_atomic_load(p, __ATOMIC_RELAXED, __HIP_MEMORY_SCOPE_AGENT);
}
__device__ __forceinline__ void stflag(unsigned* p, unsigned v){
  __hip_atomic_store(p, v, __ATOMIC_RELAXED, __HIP_MEMORY_SCOPE_AGENT);
}
// 16B coherent write-through store (full lines: fast drain, no RMW at MALL)
__device__ __forceinline__ void st128c(void* p, i32x4 v){
  asm volatile("global_store_dwordx4 %0, %1, off sc0 sc1" :: "v"(p), "v"(v) : "memory");
}

// x [B,T,D] fp32 -> X8 bf16 in [T][D/8][B][8]
__global__ void xpose_kernel(const float* __restrict__ x, unsigned short* __restrict__ X8){
  int idx   = blockIdx.x*256 + threadIdx.x;
  int t     = idx >> 11;
  int rem   = idx & 2047;
  int plane = rem >> 6;
  int b     = rem & 63;
  const float* src = x + ((size_t)b << 18) + (t << 8) + (plane << 3);
  unsigned short tmp[8];
  #pragma unroll
  for (int j = 0; j < 8; ++j) tmp[j] = f2bf(src[j]);
  int4 v; __builtin_memcpy(&v, tmp, 16);
  ((int4*)X8)[idx] = v;
}

// Contiguous K-split wave decomposition: wave w = (bh=w>>1, kh=w&1).
// Each wave computes K-half kh for BOTH 16-batch tiles of batch-half bh:
// A-reads/wave halve vs R2 (64 vs 128), global B bytes unchanged (256KB/WG).
// Layer1: kh0 = all of y (no h1 dep), kh1 = all of h1 -> post-join critical
// work is only the 2 kh1 waves. 2-way partial exchange via 8KB LDS scratch
// with ONE added __syncthreads (postF/wait syncs fence the reuse).
// h1 wait is wave-local for kh1 (each wave polls all 128 flags itself).
template<bool H0C, bool H1C>
__global__ void __launch_bounds__(TPB, 1)
lstm_mega(const float* __restrict__ Wih0, const float* __restrict__ Whh0,
          const float* __restrict__ bih0, const float* __restrict__ bhh0,
          const float* __restrict__ Wih1, const float* __restrict__ Whh1,
          const float* __restrict__ bih1, const float* __restrict__ bhh1,
          const unsigned short* __restrict__ X8,
          unsigned* flags, unsigned* gen,
          u64* H0, u64* H1, int d0, int d1,
          float* __restrict__ out)
{
  extern __shared__ char smem[];
  unsigned short* Ws = (unsigned short*)smem;     // [32][KP]
  f32x4* Sc = (f32x4*)(smem + SCR_OFF);           // [wave][64][2]

  const int tid   = threadIdx.x;
  const int wg    = blockIdx.x;
  const int layer = (wg >= NL0);
  const int wgl   = layer ? wg - NL0 : wg;
  const int KD    = layer ? K1  : K0;
  const int dlen  = layer ? HD  : DIN;
  const int KP    = layer ? K1P : K0P;
  const char* X8b = (const char*)X8;

  // ---- stage this WG's 32 gate-rows (8 cols x 4 gates) into LDS (bf16) ----
  {
    const float* Wih = layer ? Wih1 : Wih0;
    const float* Whh = layer ? Whh1 : Whh0;
    for (int m = 0; m < 32; ++m){
      int gr = (m & 3)*HD + wgl*8 + (m >> 2);      // gate-major global row
      const float* ar = Wih + (size_t)gr*dlen;
      const float* br = Whh + (size_t)gr*HD;
      unsigned short* row = Ws + m*KP;
      for (int k = tid; k < KD; k += TPB)
        row[k] = f2bf(k < dlen ? ar[k] : br[k - dlen]);
    }
  }
  __syncthreads();

  const int lane = tid & 63;
  const int wv   = tid >> 6;
  const int q    = lane >> 4;        // k-quad (A/B frags); row-quad (C/D)
  const int nn   = lane & 15;        // A-row / B-batch-col / C-batch-col
  const int bh   = wv >> 1;          // batch half
  const int kh   = wv & 1;           // K half
  const int bat0 = bh*32 + kh*16 + nn;   // batch this thread FINALIZES

  float bias[2][4];
  {
    const float* bi = layer ? bih1 : bih0;
    const float* bp = layer ? bhh1 : bhh0;
    #pragma unroll
    for (int rt = 0; rt < 2; ++rt){
      int colr = wgl*8 + rt*4 + q;
      #pragma unroll
      for (int r = 0; r < 4; ++r)
        bias[rt][r] = bi[r*HD + colr] + bp[r*HD + colr];
    }
  }

  float cst[2] = {0.f, 0.f};
  float hv[2]  = {0.f, 0.f};
  f32x4 aT0R0, aT0R1, aT1R0, aT1R1;   // [tile][row-group] partials (this K-half)

  // chunk = 4 kb-slices x 2 tiles = 16 u64 in flight (R2 register budget)
  auto LD = [&](const char* slab, int kbl, bool coh, u64* d){
    #pragma unroll
    for (int jj = 0; jj < 4; ++jj){
      const char* p = slab + ((((kbl + jj)*4 + q)*64 + bh*32 + nn) << 4);
      if (coh){
        d[4*jj+0] = ld64c((const u64*)p);
        d[4*jj+1] = ld64c((const u64*)p + 1);
        d[4*jj+2] = ld64c((const u64*)(p + 256));
        d[4*jj+3] = ld64c((const u64*)(p + 256) + 1);
      } else {
        __builtin_memcpy(&d[4*jj],   p,       16);
        __builtin_memcpy(&d[4*jj+2], p + 256, 16);
      }
    }
  };
  auto CH = [&](int kb0, u64* d){       // consume chunk: global kb kb0..kb0+3
    #pragma unroll
    for (int jj = 0; jj < 4; ++jj){
      const int kb = kb0 + jj;
      bf16x8 a0, a1, b0, b1;
      __builtin_memcpy(&a0, &Ws[nn*KP + kb*32 + q*8], 16);
      __builtin_memcpy(&a1, &Ws[(16+nn)*KP + kb*32 + q*8], 16);
      u64 t0[2] = {d[4*jj], d[4*jj+1]}, t1[2] = {d[4*jj+2], d[4*jj+3]};
      __builtin_memcpy(&b0, t0, 16);
      __builtin_memcpy(&b1, t1, 16);
      aT0R0 = __builtin_amdgcn_mfma_f32_16x16x32_bf16(a0, b0, aT0R0, 0, 0, 0);
      aT0R1 = __builtin_amdgcn_mfma_f32_16x16x32_bf16(a1, b0, aT0R1, 0, 0, 0);
      aT1R0 = __builtin_amdgcn_mfma_f32_16x16x32_bf16(a0, b1, aT1R0, 0, 0, 0);
      aT1R1 = __builtin_amdgcn_mfma_f32_16x16x32_bf16(a1, b1, aT1R1, 0, 0, 0);
    }
  };

  // ---- flag machinery (monotonic; seen-cache skips proven polls) ----
  unsigned seenA = 0, seenB = 0;
  // pollers = kh0 waves (0,2) so kh1 pre-join compute never delays detect
  auto waitL0 = [&](unsigned ep){
    if ((wv == 0 || wv == 2) && seenA < ep){
      const unsigned* p = &flags[((wv == 0 ? lane : 64 + lane))*16];
      unsigned v = ldflag(p);
      while (v < ep){ __builtin_amdgcn_s_sleep(1); v = ldflag(p); }
      seenA = v;
    }
    __syncthreads();
  };
  // wave-local join on all 128 L1 flags (2 per lane) — NO syncthreads
  auto waitL1w = [&](unsigned ep){
    if (seenB < ep){
      const unsigned* p1 = &flags[(NL0 + lane)*16];
      const unsigned* p2 = &flags[(NL0 + 64 + lane)*16];
      unsigned v1 = ldflag(p1), v2 = ldflag(p2);
      while (v1 < ep || v2 < ep){
        __builtin_amdgcn_s_sleep(1);
        if (v1 < ep) v1 = ldflag(p1);
        if (v2 < ep) v2 = ldflag(p2);
      }
      seenB = v1 < v2 ? v1 : v2;
    }
  };
  auto postF = [&](unsigned ep){
    asm volatile("s_waitcnt vmcnt(0)" ::: "memory");  // sc stores at MALL
    __syncthreads();                                  // whole WG drained
    if (tid == 0) stflag(&flags[wg*16], ep);
  };
  auto waitAll = [&](unsigned ep){                    // legacy full join (tier0)
    while (ldflag(&flags[tid*16]) < ep) __builtin_amdgcn_s_sleep(1);
    __syncthreads();
  };

  u64 B0[16], B1[16], B2[16];   // depth-3 chunk ring (proven idiom)

  // 2-way K-reduction exchange + gates + packed 16B store (R2 epilogue shape)
  auto finish = [&](u64* Hw, int wd, int t){
    // send the tile we don't finalize (tile kh^1) to partner wave wv^1
    Sc[((wv ^ 1)*64 + lane)*2 + 0] = kh ? aT0R0 : aT1R0;
    Sc[((wv ^ 1)*64 + lane)*2 + 1] = kh ? aT0R1 : aT1R1;
    __syncthreads();
    f32x4 s0 = (kh ? aT1R0 : aT0R0) + Sc[(wv*64 + lane)*2 + 0];
    f32x4 s1 = (kh ? aT1R1 : aT0R1) + Sc[(wv*64 + lane)*2 + 1];
    #pragma unroll
    for (int rt = 0; rt < 2; ++rt){
      f32x4 s = rt ? s1 : s0;
      float ii = sigmf(s[0] + bias[rt][0]);
      float ff = sigmf(s[1] + bias[rt][1]);
      float gg = tanhf_fast(s[2] + bias[rt][2]);
      float oo = sigmf(s[3] + bias[rt][3]);
      cst[rt] = ff*cst[rt] + ii*gg;
      hv[rt]  = oo*tanhf_fast(cst[rt]);
    }
    // pack 8 bf16 of one batch into one lane -> single 16B coherent store
    unsigned hpk = ((unsigned)f2bf(hv[1]) << 16) | (unsigned)f2bf(hv[0]);
    unsigned g0 = __shfl(hpk, nn);
    unsigned g1 = __shfl(hpk, nn + 16);
    unsigned g2 = __shfl(hpk, nn + 32);
    unsigned g3 = __shfl(hpk, nn + 48);
    if (q == 0){
      i32x4 v;
      v.x = (int)((g0 & 0xffffu) | (g1 << 16));       // rt0: q0,q1
      v.y = (int)((g2 & 0xffffu) | (g3 << 16));       // rt0: q2,q3
      v.z = (int)((g0 >> 16) | (g1 & 0xffff0000u));   // rt1: q0,q1
      v.w = (int)((g2 >> 16) | (g3 & 0xffff0000u));   // rt1: q2,q3
      char* wbase = (char*)(Hw + (size_t)((t+1) % wd)*HSLAB_U64);
      st128c(wbase + ((wgl*64 + bat0) << 4), v);
    }
  };

  // ---- layer 0 step: gates = W0 @ [x_t ; h0(t-1)] ----
  // kh1: x kb 0-7 (pre-join) + h kb 24-39; kh0: h kb 8-23. Balanced post-join.
  auto step0 = [&](int t, bool dec){
    aT0R0 = (f32x4){0,0,0,0}; aT0R1 = aT0R0; aT1R0 = aT0R0; aT1R1 = aT0R0;
    const char* xb = X8b + ((size_t)t << 15);
    const char* hb = (const char*)(H0 + (size_t)(t % d0)*HSLAB_U64);
    if (kh == 1){                          // x part: no dependency, pre-join
      LD(xb, 0, false, B0);
      LD(xb, 4, false, B1);
      CH(0, B0);
      CH(4, B1);
    }
    if (dec) waitL0((unsigned)t);          // own-group join: h0(t-1) ready
    const int sb = kh ? 16 : 0;            // slab kb base of this wave's h range
    const int gb = 8 + sb;                 // global kb base
    LD(hb, sb + 0, H0C, B0);
    LD(hb, sb + 4, H0C, B1);
    LD(hb, sb + 8, H0C, B2);
    CH(gb + 0, B0); LD(hb, sb + 12, H0C, B0);
    CH(gb + 4, B1);
    CH(gb + 8, B2);
    CH(gb + 12, B0);
    finish(H0, d0, t);
  };

  // ---- layer 1 step: gates = W1 @ [y0(t) ; h1(t-1)] ----
  // kh0: all y (kb 0-31, no h1 dep); kh1: all h1 (kb 32-63, post wave-local join)
  auto step1 = [&](int t, bool dec){
    aT0R0 = (f32x4){0,0,0,0}; aT0R1 = aT0R0; aT1R0 = aT0R0; aT1R1 = aT0R0;
    const char* yb  = (const char*)(H0 + (size_t)((t+1) % d0)*HSLAB_U64);
    const char* hb1 = (const char*)(H1 + (size_t)(t % d1)*HSLAB_U64);
    if (dec) waitL0((unsigned)(t+1));   // y0(t) ready — instant once L0 ahead
    if (kh == 0){
      LD(yb, 0, H0C, B0);
      LD(yb, 4, H0C, B1);
      LD(yb, 8, H0C, B2);
      CH(0,  B0); LD(yb, 12, H0C, B0);
      CH(4,  B1); LD(yb, 16, H0C, B1);
      CH(8,  B2); LD(yb, 20, H0C, B2);
      CH(12, B0); LD(yb, 24, H0C, B0);
      CH(16, B1); LD(yb, 28, H0C, B1);
      CH(20, B2);
      CH(24, B0);
      CH(28, B1);
    } else {
      if (dec) waitL1w((unsigned)t);    // h1(t-1) ready — wave-local, no WG sync
      LD(hb1, 0, H1C, B0);
      LD(hb1, 4, H1C, B1);
      LD(hb1, 8, H1C, B2);
      CH(32, B0); LD(hb1, 12, H1C, B0);
      CH(36, B1); LD(hb1, 16, H1C, B1);
      CH(40, B2); LD(hb1, 20, H1C, B2);
      CH(44, B0); LD(hb1, 24, H1C, B0);
      CH(48, B1); LD(hb1, 28, H1C, B1);
      CH(52, B2);
      CH(56, B0);
      CH(60, B1);
    }
    finish(H1, d1, t);
  };

  const bool dec = (d0 >= T_STEPS + 1);  // deep y0 ring => decoupled schedule
  if (!layer){
    if (dec){
      for (int s = 0; s < T_STEPS; ++s){ step0(s, true); postF((unsigned)(s+1)); }
    } else {
      for (int s = 0; s < T_STEPS; ++s){
        step0(s, false); postF((unsigned)(s+1)); waitAll((unsigned)(s+1));
      }
    }
  } else {
    if (dec){
      for (int t = 0; t < T_STEPS; ++t){ step1(t, true); postF((unsigned)(t+1)); }
    } else {
      for (int s = 0; s < T_STEPS; ++s){
        if (s > 0) step1(s-1, false);
        postF((unsigned)(s+1)); waitAll((unsigned)(s+1));
      }
      step1(T_STEPS-1, false);
    }
  }

  // out = [h0 | h1 | c0 | c1], each [B=64, H=1024] fp32
  {
    int col0 = wgl*8 + q;
    int base = layer ? 65536 : 0;
    out[base          + bat0*HD + col0    ] = hv[0];
    out[base          + bat0*HD + col0 + 4] = hv[1];
    out[base + 131072 + bat0*HD + col0    ] = cst[0];
    out[base + 131072 + bat0*HD + col0 + 4] = cst[1];
  }
}

extern "C" void kernel_launch(void* const* d_in, const int* in_sizes, int n_in,
                              void* d_out, int out_size, void* d_ws, size_t ws_size,
                              hipStream_t stream)
{
  const float* x    = (const float*)d_in[0];
  const float* Wih0 = (const float*)d_in[1];
  const float* Whh0 = (const float*)d_in[2];
  const float* bih0 = (const float*)d_in[3];
  const float* bhh0 = (const float*)d_in[4];
  const float* Wih1 = (const float*)d_in[5];
  const float* Whh1 = (const float*)d_in[6];
  const float* bih1 = (const float*)d_in[7];
  const float* bhh1 = (const float*)d_in[8];
  float* out = (float*)d_out;

  char* ws = (char*)d_ws;
  unsigned* flags = (unsigned*)ws;
  unsigned* gen   = (unsigned*)(ws + 16384);

  const size_t need2 = FLAGS_BYTES + 2*HIST_BYTES + X8_BYTES;               // ~302 MB
  const size_t need1 = FLAGS_BYTES + HIST_BYTES + 2*HSLAB_BYTES + X8_BYTES; // ~168 MB

  u64 *H0p, *H1p; unsigned short* X8p; int d0, d1, tier;
  if (ws_size >= need2){
    tier = 2; d0 = HIST_DEPTH; d1 = HIST_DEPTH;
    H0p = (u64*)(ws + FLAGS_BYTES);
    H1p = (u64*)(ws + FLAGS_BYTES + HIST_BYTES);
    X8p = (unsigned short*)(ws + FLAGS_BYTES + 2*HIST_BYTES);
  } else if (ws_size >= need1){
    tier = 1; d0 = HIST_DEPTH; d1 = 2;
    H0p = (u64*)(ws + FLAGS_BYTES);
    H1p = (u64*)(ws + FLAGS_BYTES + HIST_BYTES);
    X8p = (unsigned short*)(ws + FLAGS_BYTES + HIST_BYTES + 2*HSLAB_BYTES);
  } else {
    tier = 0; d0 = 2; d1 = 2;
    H0p = (u64*)(ws + FLAGS_BYTES);
    H1p = (u64*)(ws + FLAGS_BYTES + 2*HSLAB_BYTES);
    X8p = (unsigned short*)(ws + FLAGS_BYTES + 4*HSLAB_BYTES);
  }

  // zero flags + slot 0 of each h buffer (initial state h(-1)=0)
  hipMemsetAsync(flags, 0, FLAGS_BYTES, stream);
  hipMemsetAsync(H0p, 0, HSLAB_BYTES, stream);
  hipMemsetAsync(H1p, 0, HSLAB_BYTES, stream);
  xpose_kernel<<<8192, 256, 0, stream>>>(x, X8p);

  void* fn = (tier == 2) ? (void*)&lstm_mega<false,false>
           : (tier == 1) ? (void*)&lstm_mega<false,true>
                         : (void*)&lstm_mega<true,true>;
  hipFuncSetAttribute(fn, hipFuncAttributeMaxDynamicSharedMemorySize, SMEM_BYTES);

  const unsigned short* X8c = X8p;
  void* args[] = {(void*)&Wih0,(void*)&Whh0,(void*)&bih0,(void*)&bhh0,
                  (void*)&Wih1,(void*)&Whh1,(void*)&bih1,(void*)&bhh1,
                  (void*)&X8c,(void*)&flags,(void*)&gen,
                  (void*)&H0p,(void*)&H1p,(void*)&d0,(void*)&d1,(void*)&out};
  hipError_t err = hipLaunchCooperativeKernel(fn, dim3(NWG), dim3(TPB),
                                              args, SMEM_BYTES, stream);
  if (err != hipSuccess){
    // Fallback: plain launch. 256 WGs x ~136KB LDS => 1 WG/CU, grid == CU
    // count, all WGs co-resident by capacity.
    if (tier == 2)
      lstm_mega<false,false><<<dim3(NWG), dim3(TPB), SMEM_BYTES, stream>>>(
        Wih0,Whh0,bih0,bhh0,Wih1,Whh1,bih1,bhh1,X8c,flags,gen,H0p,H1p,d0,d1,out);
    else if (tier == 1)
      lstm_mega<false,true><<<dim3(NWG), dim3(TPB), SMEM_BYTES, stream>>>(
        Wih0,Whh0,bih0,bhh0,Wih1,Whh1,bih1,bhh1,X8c,flags,gen,H0p,H1p,d0,d1,out);
    else
      lstm_mega<true,true><<<dim3(NWG), dim3(TPB), SMEM_BYTES, stream>>>(
        Wih0,Whh0,bih0,bhh0,Wih1,Whh1,bih1,bhh1,X8c,flags,gen,H0p,H1p,d0,d1,out);
  }
}